// Round 11
// baseline (272.015 us; speedup 1.0000x reference)
//
#include <hip/hip_runtime.h>
#include <hip/hip_bf16.h>

using bf16 = __hip_bfloat16;
typedef __attribute__((ext_vector_type(8))) short short8;
typedef __attribute__((ext_vector_type(4))) float floatx4;

#define NB 4
#define NSEQ 4096
#define DIM 1024
#define INNER 512
#define TOK (NB * NSEQ)   // 16384

// -------------------------- memory plan (no d_ws) ---------------------------
// x buf (64 MiB fp32): PRISTINE (read by k1 + k4).
// d_out (64 MiB):
//   [0,16)   ctx_part fp32 [128][8][64][64] (k1 writes; k2 reads)
//   [16,20)  M2 bf16 [4096][512]            (k2 writes; k3 reads)
//   [20,20.5) wqT bf16 [1024][512]          (k2 writes; k3 reads)
//   [0,64)   final output                   (k4 — reads NOTHING in d_out)
// w_qkv buf (6 MiB fp32): k1 reads rows 512..1535 (w_kv), k2 reads rows
//   0..511 (wq transpose); then k3 overwrites with W2 batches 0..2 bf16.
// w_out buf (2 MiB fp32): k2 reads; then k3 overwrites with W2 batch 3 bf16.
// Launches: 4 (was 5) — each ~10us launch overhead is part of the measured
// fixed cost (~85-105us/iter inferred from R7/R10 ledgers).

__device__ inline unsigned short f2bf(float x) {
  union { bf16 h; unsigned short u; } c; c.h = __float2bfloat16(x); return c.u;
}
__device__ inline float bf2f(unsigned short u) {
  return __uint_as_float((unsigned)u << 16);
}
__device__ inline uint4 pack8(const float4 a, const float4 b) {
  union { uint4 u; unsigned short h[8]; } p;
  p.h[0] = f2bf(a.x); p.h[1] = f2bf(a.y); p.h[2] = f2bf(a.z); p.h[3] = f2bf(a.w);
  p.h[4] = f2bf(b.x); p.h[5] = f2bf(b.y); p.h[6] = f2bf(b.z); p.h[7] = f2bf(b.w);
  return p.u;
}

// async global->LDS, 16 B per lane; HW writes lane i at ldsbase + i*16.
__device__ inline void gload_lds16(const bf16* g, bf16* ldsbase) {
  __builtin_amdgcn_global_load_lds(
      (const __attribute__((address_space(1))) void*)g,
      (__attribute__((address_space(3))) void*)ldsbase, 16, 0, 0);
}

// ---------------------------------------------------------------------------
// k1: fused kv-GEMM + softmax(k) + ctx partial, fp32 inputs direct.
// Grid 1024, XCD-swizzled: m_tile = (p&7) + (p>>6)*8, h = (p>>3)&7 — the 8
// head-blocks of one m-tile stay on ONE XCD (round-robin p%8=XCD) so the
// 512 KB A-panel is L2-resident across heads (R10 measured 132 MB FETCH from
// the un-swizzled 8x re-read; predict ~75 MB).
// Staging: fp32 reg-load -> cvt -> ds_write_b128 at XOR slot (c8^wr8) — the
// R5-verified conflict-free geometry (every bank exactly 4 accesses per
// half-wave). 2-barrier K-loop, 4 blocks/CU (TLP hides staging — R0 regime).
// Epilogue identical to the R10-verified softmax+ctx (absmax 0.75).
// ---------------------------------------------------------------------------
__global__ __launch_bounds__(256, 4)
void kv_softmax_ctx(const float* __restrict__ x, const float* __restrict__ wq,
                    float* __restrict__ ctx_part) {
  __shared__ __align__(16) char smem[33280];
  bf16* As = (bf16*)smem;                                   // [128][64]
  bf16* Bs = (bf16*)(smem + 16384);                         // [128][64]
  unsigned short* skT = (unsigned short*)smem;              // [64][130]
  unsigned short* vT  = (unsigned short*)(smem + 16640);    // [64][130]

  const int tid    = threadIdx.x;
  const int p      = blockIdx.x;
  const int h      = (p >> 3) & 7;
  const int m_tile = (p & 7) + (p >> 6) * 8;   // 0..127, XCD-contiguous
  const int m0     = m_tile * 128;

  const int wave = tid >> 6;
  const int lane = tid & 63;
  const int wr   = (wave >> 1) * 64;
  const int wc   = (wave & 1) * 64;
  const int quad = lane >> 4;
  const int r16  = lane & 15;
  const int rxor = r16 & 7;
  const int wr8  = lane >> 3;     // 0..7
  const int c8   = lane & 7;
  const int wb   = wave * 8 + wr8;   // 0..31

  // A: rows l*32 + wb (l=0..3), cols c8*8..+8 fp32
  const float* Ax = x + (size_t)(m0 + wb) * 1024 + c8 * 8;
  // B rows r = l*32 + wb: r<64 -> w_qkv row 512+h*64+r (k-head);
  //                       r>=64 -> 960+h*64+r (v-head; check r=64,h=0 -> 1024)
  const float* Bx0 = wq + (size_t)(512 + h * 64 + wb) * 1024 + c8 * 8;
  const float* Bx2 = wq + (size_t)(960 + h * 64 + 64 + wb) * 1024 + c8 * 8;

  floatx4 acc[4][4];
#pragma unroll
  for (int i = 0; i < 4; ++i)
#pragma unroll
    for (int j = 0; j < 4; ++j) acc[i][j] = (floatx4)0.0f;

  for (int kt = 0; kt < 16; ++kt) {
    const int k0 = kt << 6;
    float4 r[8];
    // ---- A: load fp32, cvt, conflict-free b128 write (prior MFMA reads
    //      ended at last iteration's trailing barrier).
#pragma unroll
    for (int l = 0; l < 4; ++l) {
      r[2 * l]     = *(const float4*)(Ax + (size_t)l * 32768 + k0);
      r[2 * l + 1] = *(const float4*)(Ax + (size_t)l * 32768 + k0 + 4);
    }
#pragma unroll
    for (int l = 0; l < 4; ++l) {
      const int row = l * 32 + wb;        // row&7 == wr8
      *(uint4*)(As + row * 64 + ((c8 ^ wr8) << 3)) = pack8(r[2 * l], r[2 * l + 1]);
    }
    // ---- B: same, reusing the register block
#pragma unroll
    for (int l = 0; l < 4; ++l) {
      const float* bp = (l < 2) ? (Bx0 + (size_t)l * 32768)
                                : (Bx2 + (size_t)(l - 2) * 32768);
      r[2 * l]     = *(const float4*)(bp + k0);
      r[2 * l + 1] = *(const float4*)(bp + k0 + 4);
    }
#pragma unroll
    for (int l = 0; l < 4; ++l) {
      const int row = l * 32 + wb;
      *(uint4*)(Bs + row * 64 + ((c8 ^ wr8) << 3)) = pack8(r[2 * l], r[2 * l + 1]);
    }
    __syncthreads();   // staging visible to all waves
#pragma unroll
    for (int kk = 0; kk < 64; kk += 32) {
      const int cbase = kk >> 3;
      short8 af[4], bfg[4];
#pragma unroll
      for (int i = 0; i < 4; ++i)
        af[i] = *(const short8*)(As + (wr + i * 16 + r16) * 64 + (((quad + cbase) ^ rxor) << 3));
#pragma unroll
      for (int j = 0; j < 4; ++j)
        bfg[j] = *(const short8*)(Bs + (wc + j * 16 + r16) * 64 + (((quad + cbase) ^ rxor) << 3));
#pragma unroll
      for (int i = 0; i < 4; ++i)
#pragma unroll
        for (int j = 0; j < 4; ++j)
          acc[i][j] = __builtin_amdgcn_mfma_f32_16x16x32_bf16(af[i], bfg[j], acc[i][j], 0, 0, 0);
    }
    __syncthreads();   // all LDS reads done -> next staging / skT-vT overlay safe
  }

  // ---- epilogue: softmax (k-waves) / passthrough (v-waves), transposed store
  const int rowbase = wr + quad * 4;
  if ((wave & 1) == 0) {
#pragma unroll
    for (int i = 0; i < 4; ++i)
#pragma unroll
      for (int reg = 0; reg < 4; ++reg) {
        float kf[4];
#pragma unroll
        for (int j = 0; j < 4; ++j) kf[j] = bf2f(f2bf(acc[i][j][reg]));
        float mx = fmaxf(fmaxf(kf[0], kf[1]), fmaxf(kf[2], kf[3]));
        mx = fmaxf(mx, __shfl_xor(mx, 1, 64));
        mx = fmaxf(mx, __shfl_xor(mx, 2, 64));
        mx = fmaxf(mx, __shfl_xor(mx, 4, 64));
        mx = fmaxf(mx, __shfl_xor(mx, 8, 64));
        float e[4]; float s = 0.0f;
#pragma unroll
        for (int j = 0; j < 4; ++j) { e[j] = __expf(kf[j] - mx); s += e[j]; }
        s += __shfl_xor(s, 1, 64);
        s += __shfl_xor(s, 2, 64);
        s += __shfl_xor(s, 4, 64);
        s += __shfl_xor(s, 8, 64);
        const float inv = 1.0f / s;
        const int row = rowbase + i * 16 + reg;
#pragma unroll
        for (int j = 0; j < 4; ++j)
          skT[(j * 16 + r16) * 130 + row] = f2bf(e[j] * inv);
      }
  } else {
#pragma unroll
    for (int i = 0; i < 4; ++i)
#pragma unroll
      for (int reg = 0; reg < 4; ++reg) {
        const int row = rowbase + i * 16 + reg;
#pragma unroll
        for (int j = 0; j < 4; ++j)
          vT[(j * 16 + r16) * 130 + row] = f2bf(acc[i][j][reg]);
      }
  }
  __syncthreads();

  // ---- ctx MFMA: ctx[d][e] = sum over 128 rows of sk[row][d]*v[row][e]
  const int d0 = wave * 16;
  floatx4 cacc[4];
#pragma unroll
  for (int j = 0; j < 4; ++j) cacc[j] = (floatx4)0.0f;
#pragma unroll
  for (int kk = 0; kk < 4; ++kk) {
    const int kof = kk * 32 + quad * 8;
    union { short8 v; unsigned u[4]; } afr;
    {
      const unsigned* qa = (const unsigned*)(skT + (d0 + r16) * 130 + kof);
      afr.u[0] = qa[0]; afr.u[1] = qa[1]; afr.u[2] = qa[2]; afr.u[3] = qa[3];
    }
#pragma unroll
    for (int j = 0; j < 4; ++j) {
      union { short8 v; unsigned u[4]; } bfr;
      const unsigned* qb = (const unsigned*)(vT + (j * 16 + r16) * 130 + kof);
      bfr.u[0] = qb[0]; bfr.u[1] = qb[1]; bfr.u[2] = qb[2]; bfr.u[3] = qb[3];
      cacc[j] = __builtin_amdgcn_mfma_f32_16x16x32_bf16(afr.v, bfr.v, cacc[j], 0, 0, 0);
    }
  }

  float* cg = ctx_part + (size_t)(m_tile * 8 + h) * 4096;
#pragma unroll
  for (int j = 0; j < 4; ++j) {
    const int e = j * 16 + r16;
#pragma unroll
    for (int r = 0; r < 4; ++r) {
      const int d = d0 + quad * 4 + r;
      cg[d * 64 + e] = cacc[j][r];
    }
  }
}

// ---------------------------------------------------------------------------
// k2 (merged): blocks [0,256) build_m2; blocks [256,384) wqT transpose.
// build_m2: M2[b*1024+o][h*64+d] = sum_e w_out[o][h*64+e] * ctx[b,h][d][e],
// ctx[b,h] = sum of the batch's 32 m-tile partials (summed during staging).
// transpose: wqT[c][c'] = bf16(wq[c'][c]); wq fp32 [512][1024] pristine.
// ---------------------------------------------------------------------------
__global__ __launch_bounds__(256)
void build_m2_wqt(const float* __restrict__ w_out, const float* __restrict__ ctx_part,
                  const float* __restrict__ wq, bf16* __restrict__ M2,
                  bf16* __restrict__ wqT) {
  const int tid = threadIdx.x;
  const int blk = blockIdx.x;

  if (blk < 256) {
    __shared__ unsigned short wo_s[128 * 68];
    __shared__ __align__(16) float ctx_s[4096];

    const int bh = blk >> 3;
    const int b  = bh >> 3, h = bh & 7;
    const int o0 = (blk & 7) * 128;

#pragma unroll
    for (int l = 0; l < 8; ++l) {
      const int s = l * 256 + tid;
      const int row = s >> 4, col4 = s & 15;
      const float4 v = *(const float4*)(w_out + (size_t)(o0 + row) * 512 + h * 64 + col4 * 4);
      wo_s[row * 68 + col4 * 4 + 0] = f2bf(v.x);
      wo_s[row * 68 + col4 * 4 + 1] = f2bf(v.y);
      wo_s[row * 68 + col4 * 4 + 2] = f2bf(v.z);
      wo_s[row * 68 + col4 * 4 + 3] = f2bf(v.w);
    }
    // ctx_s = sum of 32 m-tile partials (partial (b*32+sl, h), stride 8*4096)
    const float4* cg = (const float4*)(ctx_part + (size_t)(b * 256 + h) * 4096);
#pragma unroll
    for (int l = 0; l < 4; ++l) {
      const int idx = l * 256 + tid;
      float4 s = make_float4(0.f, 0.f, 0.f, 0.f);
#pragma unroll
      for (int sl = 0; sl < 32; ++sl) {
        const float4 v = cg[(size_t)sl * 8192 + idx];
        s.x += v.x; s.y += v.y; s.z += v.z; s.w += v.w;
      }
      ((float4*)ctx_s)[idx] = s;
    }
    __syncthreads();

    const int o_loc = tid & 127;
    const int dbase = (tid >> 7) * 32;
    float acc[32];
#pragma unroll
    for (int d = 0; d < 32; ++d) acc[d] = 0.0f;

    for (int e = 0; e < 64; ++e) {
      const float wf = bf2f(wo_s[o_loc * 68 + e]);
#pragma unroll
      for (int d = 0; d < 32; ++d)
        acc[d] += wf * ctx_s[(dbase + d) * 64 + e];
    }

    union { uint4 u[4]; unsigned short hh[32]; } o;
#pragma unroll
    for (int d = 0; d < 32; ++d) o.hh[d] = f2bf(acc[d]);
    unsigned short* dst = (unsigned short*)M2 + (size_t)(b * 1024 + o0 + o_loc) * 512 + h * 64 + dbase;
#pragma unroll
    for (int i = 0; i < 4; ++i) ((uint4*)dst)[i] = o.u[i];
  } else {
    __shared__ unsigned short t[64 * 68];
    const int q  = blk - 256;          // 0..127
    const int c0 = (q & 15) * 64;
    const int r0 = (q >> 4) * 64;
#pragma unroll
    for (int l = 0; l < 4; ++l) {
      const int s = l * 256 + tid;
      const int row = s >> 4, col4 = s & 15;
      const float4 v = *(const float4*)(wq + (size_t)(r0 + row) * 1024 + c0 + col4 * 4);
      t[row * 68 + col4 * 4 + 0] = f2bf(v.x);
      t[row * 68 + col4 * 4 + 1] = f2bf(v.y);
      t[row * 68 + col4 * 4 + 2] = f2bf(v.z);
      t[row * 68 + col4 * 4 + 3] = f2bf(v.w);
    }
    __syncthreads();
#pragma unroll
    for (int l = 0; l < 2; ++l) {
      const int s = l * 256 + tid;
      const int cc = s >> 3, g = s & 7;
      union { uint4 u; unsigned short hh[8]; } o;
#pragma unroll
      for (int u = 0; u < 8; ++u) o.hh[u] = t[(g * 8 + u) * 68 + cc];
      *(uint4*)((unsigned short*)wqT + (size_t)(c0 + cc) * 512 + r0 + g * 8) = o.u;
    }
  }
}

// ---------------------------------------------------------------------------
// k3: 128x128 bf16 GEMM (W2 = M2 @ wqT^T). Rows >= msplit go to Calt.
// Unchanged proven kernel (4 blocks/CU, gload_lds staging, XOR swizzle).
// ---------------------------------------------------------------------------
template <typename TO>
__global__ __launch_bounds__(256, 4)
void gemm_bt(const bf16* __restrict__ A, int lda,
             const bf16* __restrict__ W, int mTiles,
             TO* __restrict__ C, int ldc, int K,
             TO* __restrict__ Calt, int msplit) {
  __shared__ __align__(16) bf16 As[128 * 64];
  __shared__ __align__(16) bf16 Bs[128 * 64];

  const int tid    = threadIdx.x;
  const int p      = blockIdx.x;
  const int m_tile = p % mTiles;
  const int n_tile = p / mTiles;
  const int m0     = m_tile * 128;
  const int n0     = n_tile * 128;

  const int wave = tid >> 6;
  const int lane = tid & 63;
  const int wr   = (wave >> 1) * 64;
  const int wc   = (wave & 1) * 64;
  const int quad = lane >> 4;
  const int r16  = lane & 15;
  const int rxor = r16 & 7;
  const int lrow = lane >> 3;
  const int lcol = lane & 7;
  const int gchunk = lcol ^ lrow;

  floatx4 acc[4][4];
#pragma unroll
  for (int i = 0; i < 4; ++i)
#pragma unroll
    for (int j = 0; j < 4; ++j) acc[i][j] = (floatx4)0.0f;

  const int ksteps = K >> 6;
  for (int kt = 0; kt < ksteps; ++kt) {
    const int k0 = kt << 6;
#pragma unroll
    for (int t = 0; t < 4; ++t) {
      const int s   = wave * 4 + t;
      const int row = s * 8 + lrow;
      gload_lds16(A + (size_t)(m0 + row) * lda + k0 + gchunk * 8, As + s * 512);
      gload_lds16(W + (size_t)(n0 + row) * K   + k0 + gchunk * 8, Bs + s * 512);
    }
    __syncthreads();
#pragma unroll
    for (int kk = 0; kk < 64; kk += 32) {
      const int cbase = kk >> 3;
      short8 af[4], bfg[4];
#pragma unroll
      for (int i = 0; i < 4; ++i)
        af[i] = *(const short8*)(As + (wr + i * 16 + r16) * 64 + (((quad + cbase) ^ rxor) << 3));
#pragma unroll
      for (int j = 0; j < 4; ++j)
        bfg[j] = *(const short8*)(Bs + (wc + j * 16 + r16) * 64 + (((quad + cbase) ^ rxor) << 3));
#pragma unroll
      for (int i = 0; i < 4; ++i)
#pragma unroll
        for (int j = 0; j < 4; ++j)
          acc[i][j] = __builtin_amdgcn_mfma_f32_16x16x32_bf16(af[i], bfg[j], acc[i][j], 0, 0, 0);
    }
    __syncthreads();
  }

  TO* Cb = C; int radj = 0;
  if (Calt && m0 >= msplit) { Cb = Calt; radj = msplit; }
#pragma unroll
  for (int j = 0; j < 4; ++j) {
    const int col = n0 + wc + j * 16 + r16;
#pragma unroll
    for (int i = 0; i < 4; ++i) {
      const int rowb = m0 + wr + i * 16 + quad * 4 - radj;
#pragma unroll
      for (int r = 0; r < 4; ++r)
        Cb[(size_t)(rowb + r) * ldc + col] = __float2bfloat16(acc[i][j][r]);
    }
  }
}

// ---------------------------------------------------------------------------
// k4: out = bf16(A_fp32) @ W2[batch]^T + bias. 128x128 tiles, grid 1024
// (128 m-tiles x 8 n-tiles), XCD-swizzled like k1 so the 512 KB fp32 A-panel
// is shared across the 8 n-blocks on one XCD. A: fp32 reg-stage + cvt +
// conflict-free b128 ds_write (same template as k1). B: bf16 gload_lds
// (gemm_bt staging). 2 barriers/K-step, 4 blocks/CU. K=1024 fixed.
// ---------------------------------------------------------------------------
__global__ __launch_bounds__(256, 4)
void gemm_f32a(const float* __restrict__ A,
               const bf16* __restrict__ W, size_t wbatch,
               const bf16* __restrict__ Walt,
               const float* __restrict__ bias,
               float* __restrict__ C, int ldc) {
  __shared__ __align__(16) bf16 As[128 * 64];
  __shared__ __align__(16) bf16 Bs[128 * 64];

  const int tid    = threadIdx.x;
  const int p      = blockIdx.x;
  const int n_tile = (p >> 3) & 7;
  const int m_tile = (p & 7) + (p >> 6) * 8;   // 0..127, XCD-contiguous
  const int m0 = m_tile * 128, n0 = n_tile * 128;
  const int batch = m_tile >> 5;
  const bf16* Wp = (batch == 3 && Walt) ? Walt : W + (size_t)batch * wbatch;

  const int wave = tid >> 6;
  const int lane = tid & 63;
  const int wr   = (wave >> 1) * 64;
  const int wc   = (wave & 1) * 64;
  const int quad = lane >> 4;
  const int r16  = lane & 15;
  const int rxor = r16 & 7;
  const int lrow = lane >> 3;     // == wr8
  const int lcol = lane & 7;      // == c8
  const int gchunk = lcol ^ lrow;
  const int wb = wave * 8 + lrow;

  const float* Ax = A + (size_t)(m0 + wb) * 1024 + lcol * 8;

  floatx4 acc[4][4];
#pragma unroll
  for (int i = 0; i < 4; ++i)
#pragma unroll
    for (int j = 0; j < 4; ++j) acc[i][j] = (floatx4)0.0f;

  for (int kt = 0; kt < 16; ++kt) {
    const int k0 = kt << 6;
    float4 rA[8];
#pragma unroll
    for (int l = 0; l < 4; ++l) {
      rA[2 * l]     = *(const float4*)(Ax + (size_t)l * 32768 + k0);
      rA[2 * l + 1] = *(const float4*)(Ax + (size_t)l * 32768 + k0 + 4);
    }
#pragma unroll
    for (int t = 0; t < 4; ++t) {
      const int s   = wave * 4 + t;
      const int row = s * 8 + lrow;
      gload_lds16(Wp + (size_t)(n0 + row) * 1024 + k0 + gchunk * 8, Bs + s * 512);
    }
#pragma unroll
    for (int l = 0; l < 4; ++l) {
      const int row = l * 32 + wb;       // row&7 == lrow
      *(uint4*)(As + row * 64 + ((lcol ^ lrow) << 3)) = pack8(rA[2 * l], rA[2 * l + 1]);
    }
    __syncthreads();   // drains vm (Bs landed) + lgkm (As writes visible)
#pragma unroll
    for (int kk = 0; kk < 64; kk += 32) {
      const int cbase = kk >> 3;
      short8 af[4], bfg[4];
#pragma unroll
      for (int i = 0; i < 4; ++i)
        af[i] = *(const short8*)(As + (wr + i * 16 + r16) * 64 + (((quad + cbase) ^ rxor) << 3));
#pragma unroll
      for (int j = 0; j < 4; ++j)
        bfg[j] = *(const short8*)(Bs + (wc + j * 16 + r16) * 64 + (((quad + cbase) ^ rxor) << 3));
#pragma unroll
      for (int i = 0; i < 4; ++i)
#pragma unroll
        for (int j = 0; j < 4; ++j)
          acc[i][j] = __builtin_amdgcn_mfma_f32_16x16x32_bf16(af[i], bfg[j], acc[i][j], 0, 0, 0);
    }
    __syncthreads();
  }

  // D mapping (verified m89/m91): row = quad*4 + reg, col = lane&15
#pragma unroll
  for (int j = 0; j < 4; ++j) {
    const int col = n0 + wc + j * 16 + r16;
    const float bv = bias[col];
#pragma unroll
    for (int i = 0; i < 4; ++i) {
      const int rowb = m0 + wr + i * 16 + quad * 4;
#pragma unroll
      for (int r = 0; r < 4; ++r)
        C[(size_t)(rowb + r) * ldc + col] = acc[i][j][r] + bv;
    }
  }
}

// ---------------------------------------------------------------------------
extern "C" void kernel_launch(void* const* d_in, const int* in_sizes, int n_in,
                              void* d_out, int out_size, void* d_ws, size_t ws_size,
                              hipStream_t stream) {
  const float* x     = (const float*)d_in[0];
  const float* w_qkv = (const float*)d_in[1];
  const float* w_out = (const float*)d_in[2];
  const float* b_out = (const float*)d_in[3];
  float* out = (float*)d_out;

  char* wbuf = (char*)d_in[1];
  char* obuf = (char*)d_out;

  float* ctxp = (float*)obuf;                        // d_out[0,16)
  bf16*  M2   = (bf16*)(obuf + (size_t)16777216);    // d_out[16,20)
  bf16*  wqT  = (bf16*)(obuf + (size_t)20971520);    // d_out[20,20.5)
  bf16*  W2   = (bf16*)wbuf;                         // wbuf[0,6): batches 0-2
  bf16*  W2b3 = (bf16*)d_in[2];                      // w_out buf: batch 3

  // 1) fused kv-GEMM + softmax + ctx partials (fp32 inputs direct, no prep)
  kv_softmax_ctx<<<1024, 256, 0, stream>>>(x, w_qkv, ctxp);

  // 2) merged: M2 = w_out folded through summed ctx; wqT = wq^T
  build_m2_wqt<<<384, 256, 0, stream>>>(w_out, ctxp, w_qkv, M2, wqT);

  // 3) W2 = M2 @ wqT^T; rows<3072 -> wbuf[0,6), rows>=3072 -> w_out buf.
  gemm_bt<bf16><<<256, 256, 0, stream>>>(
      M2, 512, wqT, 32, W2, 1024, 512, W2b3, 3072);

  // 4) out = bf16(x) @ W2[b]^T + b_out -> d_out (reads nothing in d_out).
  gemm_f32a<<<1024, 256, 0, stream>>>(
      x, W2, (size_t)1048576, W2b3, b_out, out, DIM);
}

// Round 14
// 259.978 us; speedup vs baseline: 1.0463x; 1.0463x over previous
//
#include <hip/hip_runtime.h>
#include <hip/hip_bf16.h>

using bf16 = __hip_bfloat16;
typedef __attribute__((ext_vector_type(8))) short short8;
typedef __attribute__((ext_vector_type(4))) float floatx4;

#define NB 4
#define NSEQ 4096
#define DIM 1024
#define INNER 512
#define TOK (NB * NSEQ)   // 16384

// -------------------------- memory plan (no d_ws) ---------------------------
// x buf (64 MiB fp32): PRISTINE (read by k1 + k4).
// d_out (64 MiB):
//   [0,16)   ctx_part fp32 [128][8][64][64] (k1 writes; k2 reads)
//   [16,20)  M2 bf16 [4096][512]            (k2 writes; k3 reads)
//   [20,20.5) wqT bf16 [1024][512]          (k2 writes; k3 reads)
//   [22,24)  wkvb bf16 [1024][1024]         (k0 writes; k1 reads)
//   [0,64)   final output                   (k4 — reads NOTHING in d_out)
// w_qkv buf (6 MiB fp32): k0 reads rows 512..1535 (w_kv), k2 reads rows
//   0..511 (wq transpose); then k3 overwrites with W2 batches 0..2 bf16.
// w_out buf (2 MiB fp32): k2 reads; then k3 overwrites with W2 batch 3 bf16.
// Launches: 5. R7/R10/R11 ledgers all show ~95-105us fixed per-iteration
// overhead (graph replay + 64MB out memset + input restore) independent of
// launch count 4 vs 6 — so the tiny k0 costs ~launch-gap only.

__device__ inline unsigned short f2bf(float x) {
  union { bf16 h; unsigned short u; } c; c.h = __float2bfloat16(x); return c.u;
}
__device__ inline float bf2f(unsigned short u) {
  return __uint_as_float((unsigned)u << 16);
}
__device__ inline uint4 pack8(const float4 a, const float4 b) {
  union { uint4 u; unsigned short h[8]; } p;
  p.h[0] = f2bf(a.x); p.h[1] = f2bf(a.y); p.h[2] = f2bf(a.z); p.h[3] = f2bf(a.w);
  p.h[4] = f2bf(b.x); p.h[5] = f2bf(b.y); p.h[6] = f2bf(b.z); p.h[7] = f2bf(b.w);
  return p.u;
}

// async global->LDS, 16 B per lane; HW writes lane i at ldsbase + i*16.
__device__ inline void gload_lds16(const bf16* g, bf16* ldsbase) {
  __builtin_amdgcn_global_load_lds(
      (const __attribute__((address_space(1))) void*)g,
      (__attribute__((address_space(3))) void*)ldsbase, 16, 0, 0);
}

// ---------------------------------------------------------------------------
// k0: mini prep — wkvb = bf16(w_qkv rows 512..1535). 2 MB write, ~2-3us.
// ---------------------------------------------------------------------------
__global__ __launch_bounds__(256)
void conv_wkv(const float* __restrict__ w_qkv, bf16* __restrict__ wkvb) {
  const size_t i = (size_t)blockIdx.x * 256 + threadIdx.x;
  const float* src = w_qkv + (size_t)INNER * DIM + i * 8;
  const float4 a = ((const float4*)src)[0];
  const float4 b = ((const float4*)src)[1];
  *(uint4*)(wkvb + i * 8) = pack8(a, b);
}

// ---------------------------------------------------------------------------
// k1: fused kv-GEMM + softmax(k) + ctx partial.
// A = fp32 x, reg-staged (R11-verified geometry: rows l*32+wb, cols c8*8,
// conflict-free b128 write at XOR slot c8^wr8 — 0 extra bank conflicts).
// B = bf16 wkvb via ASYNC gload_lds (R10-verified badd mapping) — issued
// FIRST so its latency rides under A's load+cvt; only ONE synchronous load
// round-trip (A) per K-tile [R11 post-mortem: the serial A->B reg reuse +
// doubled cvt was the 58->95us regression].
// XCD swizzle (R11-proven: FETCH 132->49 MB): m_tile=(p&7)+(p>>6)*8,
// h=(p>>3)&7 — all 8 head-blocks of an m-tile on one XCD, A-panel L2-shared.
// Epilogue: R10/R11-verified softmax+ctx (absmax 0.75).
// ---------------------------------------------------------------------------
__global__ __launch_bounds__(256, 4)
void kv_softmax_ctx(const float* __restrict__ x, const bf16* __restrict__ wkvb,
                    float* __restrict__ ctx_part) {
  __shared__ __align__(16) char smem[33280];
  bf16* As = (bf16*)smem;                                   // [128][64]
  bf16* Bs = (bf16*)(smem + 16384);                         // [128][64]
  unsigned short* skT = (unsigned short*)smem;              // [64][130]
  unsigned short* vT  = (unsigned short*)(smem + 16640);    // [64][130]

  const int tid    = threadIdx.x;
  const int p      = blockIdx.x;
  const int h      = (p >> 3) & 7;
  const int m_tile = (p & 7) + (p >> 6) * 8;   // 0..127, XCD-contiguous
  const int m0     = m_tile * 128;

  const int wave = tid >> 6;
  const int lane = tid & 63;
  const int wr   = (wave >> 1) * 64;
  const int wc   = (wave & 1) * 64;
  const int quad = lane >> 4;
  const int r16  = lane & 15;
  const int rxor = r16 & 7;
  const int lrow = lane >> 3;     // wr8, 0..7
  const int lcol = lane & 7;      // c8
  const int gchunk = lcol ^ lrow;
  const int wb   = wave * 8 + lrow;   // 0..31

  // A: rows l*32 + wb (l=0..3), cols lcol*8..+8 fp32
  const float* Ax = x + (size_t)(m0 + wb) * 1024 + lcol * 8;

  floatx4 acc[4][4];
#pragma unroll
  for (int i = 0; i < 4; ++i)
#pragma unroll
    for (int j = 0; j < 4; ++j) acc[i][j] = (floatx4)0.0f;

  for (int kt = 0; kt < 16; ++kt) {
    const int k0 = kt << 6;
    // ---- B first: async bf16 global->LDS (rows 0-63 k-head, 64-127 v-head)
#pragma unroll
    for (int t = 0; t < 4; ++t) {
      const int s   = wave * 4 + t;
      const int row = s * 8 + lrow;
      const int badd = (s * 8 >= 64) ? (448 + h * 64) : (h * 64);
      gload_lds16(wkvb + (size_t)(badd + row) * 1024 + k0 + gchunk * 8, Bs + s * 512);
    }
    // ---- A: fp32 load -> cvt -> conflict-free b128 write (LDS free since
    //      last iteration's trailing barrier)
    float4 rA[8];
#pragma unroll
    for (int l = 0; l < 4; ++l) {
      rA[2 * l]     = *(const float4*)(Ax + (size_t)l * 32768 + k0);
      rA[2 * l + 1] = *(const float4*)(Ax + (size_t)l * 32768 + k0 + 4);
    }
#pragma unroll
    for (int l = 0; l < 4; ++l) {
      const int row = l * 32 + wb;        // row&7 == lrow
      *(uint4*)(As + row * 64 + ((lcol ^ lrow) << 3)) = pack8(rA[2 * l], rA[2 * l + 1]);
    }
    __syncthreads();   // drains vm (Bs landed) + lgkm (As writes visible)
#pragma unroll
    for (int kk = 0; kk < 64; kk += 32) {
      const int cbase = kk >> 3;
      short8 af[4], bfg[4];
#pragma unroll
      for (int i = 0; i < 4; ++i)
        af[i] = *(const short8*)(As + (wr + i * 16 + r16) * 64 + (((quad + cbase) ^ rxor) << 3));
#pragma unroll
      for (int j = 0; j < 4; ++j)
        bfg[j] = *(const short8*)(Bs + (wc + j * 16 + r16) * 64 + (((quad + cbase) ^ rxor) << 3));
#pragma unroll
      for (int i = 0; i < 4; ++i)
#pragma unroll
        for (int j = 0; j < 4; ++j)
          acc[i][j] = __builtin_amdgcn_mfma_f32_16x16x32_bf16(af[i], bfg[j], acc[i][j], 0, 0, 0);
    }
    __syncthreads();   // all LDS reads done -> next staging / skT-vT overlay safe
  }

  // ---- epilogue: softmax (k-waves) / passthrough (v-waves), transposed store
  const int rowbase = wr + quad * 4;
  if ((wave & 1) == 0) {
#pragma unroll
    for (int i = 0; i < 4; ++i)
#pragma unroll
      for (int reg = 0; reg < 4; ++reg) {
        float kf[4];
#pragma unroll
        for (int j = 0; j < 4; ++j) kf[j] = bf2f(f2bf(acc[i][j][reg]));
        float mx = fmaxf(fmaxf(kf[0], kf[1]), fmaxf(kf[2], kf[3]));
        mx = fmaxf(mx, __shfl_xor(mx, 1, 64));
        mx = fmaxf(mx, __shfl_xor(mx, 2, 64));
        mx = fmaxf(mx, __shfl_xor(mx, 4, 64));
        mx = fmaxf(mx, __shfl_xor(mx, 8, 64));
        float e[4]; float s = 0.0f;
#pragma unroll
        for (int j = 0; j < 4; ++j) { e[j] = __expf(kf[j] - mx); s += e[j]; }
        s += __shfl_xor(s, 1, 64);
        s += __shfl_xor(s, 2, 64);
        s += __shfl_xor(s, 4, 64);
        s += __shfl_xor(s, 8, 64);
        const float inv = 1.0f / s;
        const int row = rowbase + i * 16 + reg;
#pragma unroll
        for (int j = 0; j < 4; ++j)
          skT[(j * 16 + r16) * 130 + row] = f2bf(e[j] * inv);
      }
  } else {
#pragma unroll
    for (int i = 0; i < 4; ++i)
#pragma unroll
      for (int reg = 0; reg < 4; ++reg) {
        const int row = rowbase + i * 16 + reg;
#pragma unroll
        for (int j = 0; j < 4; ++j)
          vT[(j * 16 + r16) * 130 + row] = f2bf(acc[i][j][reg]);
      }
  }
  __syncthreads();

  // ---- ctx MFMA: ctx[d][e] = sum over 128 rows of sk[row][d]*v[row][e]
  const int d0 = wave * 16;
  floatx4 cacc[4];
#pragma unroll
  for (int j = 0; j < 4; ++j) cacc[j] = (floatx4)0.0f;
#pragma unroll
  for (int kk = 0; kk < 4; ++kk) {
    const int kof = kk * 32 + quad * 8;
    union { short8 v; unsigned u[4]; } afr;
    {
      const unsigned* qa = (const unsigned*)(skT + (d0 + r16) * 130 + kof);
      afr.u[0] = qa[0]; afr.u[1] = qa[1]; afr.u[2] = qa[2]; afr.u[3] = qa[3];
    }
#pragma unroll
    for (int j = 0; j < 4; ++j) {
      union { short8 v; unsigned u[4]; } bfr;
      const unsigned* qb = (const unsigned*)(vT + (j * 16 + r16) * 130 + kof);
      bfr.u[0] = qb[0]; bfr.u[1] = qb[1]; bfr.u[2] = qb[2]; bfr.u[3] = qb[3];
      cacc[j] = __builtin_amdgcn_mfma_f32_16x16x32_bf16(afr.v, bfr.v, cacc[j], 0, 0, 0);
    }
  }

  float* cg = ctx_part + (size_t)(m_tile * 8 + h) * 4096;
#pragma unroll
  for (int j = 0; j < 4; ++j) {
    const int e = j * 16 + r16;
#pragma unroll
    for (int r = 0; r < 4; ++r) {
      const int d = d0 + quad * 4 + r;
      cg[d * 64 + e] = cacc[j][r];
    }
  }
}

// ---------------------------------------------------------------------------
// k2 (merged): blocks [0,256) build_m2; blocks [256,384) wqT transpose.
// ---------------------------------------------------------------------------
__global__ __launch_bounds__(256)
void build_m2_wqt(const float* __restrict__ w_out, const float* __restrict__ ctx_part,
                  const float* __restrict__ wq, bf16* __restrict__ M2,
                  bf16* __restrict__ wqT) {
  const int tid = threadIdx.x;
  const int blk = blockIdx.x;

  if (blk < 256) {
    __shared__ unsigned short wo_s[128 * 68];
    __shared__ __align__(16) float ctx_s[4096];

    const int bh = blk >> 3;
    const int b  = bh >> 3, h = bh & 7;
    const int o0 = (blk & 7) * 128;

#pragma unroll
    for (int l = 0; l < 8; ++l) {
      const int s = l * 256 + tid;
      const int row = s >> 4, col4 = s & 15;
      const float4 v = *(const float4*)(w_out + (size_t)(o0 + row) * 512 + h * 64 + col4 * 4);
      wo_s[row * 68 + col4 * 4 + 0] = f2bf(v.x);
      wo_s[row * 68 + col4 * 4 + 1] = f2bf(v.y);
      wo_s[row * 68 + col4 * 4 + 2] = f2bf(v.z);
      wo_s[row * 68 + col4 * 4 + 3] = f2bf(v.w);
    }
    // ctx_s = sum of 32 m-tile partials (partial (b*32+sl, h), stride 8*4096)
    const float4* cg = (const float4*)(ctx_part + (size_t)(b * 256 + h) * 4096);
#pragma unroll
    for (int l = 0; l < 4; ++l) {
      const int idx = l * 256 + tid;
      float4 s = make_float4(0.f, 0.f, 0.f, 0.f);
#pragma unroll
      for (int sl = 0; sl < 32; ++sl) {
        const float4 v = cg[(size_t)sl * 8192 + idx];
        s.x += v.x; s.y += v.y; s.z += v.z; s.w += v.w;
      }
      ((float4*)ctx_s)[idx] = s;
    }
    __syncthreads();

    const int o_loc = tid & 127;
    const int dbase = (tid >> 7) * 32;
    float acc[32];
#pragma unroll
    for (int d = 0; d < 32; ++d) acc[d] = 0.0f;

    for (int e = 0; e < 64; ++e) {
      const float wf = bf2f(wo_s[o_loc * 68 + e]);
#pragma unroll
      for (int d = 0; d < 32; ++d)
        acc[d] += wf * ctx_s[(dbase + d) * 64 + e];
    }

    union { uint4 u[4]; unsigned short hh[32]; } o;
#pragma unroll
    for (int d = 0; d < 32; ++d) o.hh[d] = f2bf(acc[d]);
    unsigned short* dst = (unsigned short*)M2 + (size_t)(b * 1024 + o0 + o_loc) * 512 + h * 64 + dbase;
#pragma unroll
    for (int i = 0; i < 4; ++i) ((uint4*)dst)[i] = o.u[i];
  } else {
    __shared__ unsigned short t[64 * 68];
    const int q  = blk - 256;          // 0..127
    const int c0 = (q & 15) * 64;
    const int r0 = (q >> 4) * 64;
#pragma unroll
    for (int l = 0; l < 4; ++l) {
      const int s = l * 256 + tid;
      const int row = s >> 4, col4 = s & 15;
      const float4 v = *(const float4*)(wq + (size_t)(r0 + row) * 1024 + c0 + col4 * 4);
      t[row * 68 + col4 * 4 + 0] = f2bf(v.x);
      t[row * 68 + col4 * 4 + 1] = f2bf(v.y);
      t[row * 68 + col4 * 4 + 2] = f2bf(v.z);
      t[row * 68 + col4 * 4 + 3] = f2bf(v.w);
    }
    __syncthreads();
#pragma unroll
    for (int l = 0; l < 2; ++l) {
      const int s = l * 256 + tid;
      const int cc = s >> 3, g = s & 7;
      union { uint4 u; unsigned short hh[8]; } o;
#pragma unroll
      for (int u = 0; u < 8; ++u) o.hh[u] = t[(g * 8 + u) * 68 + cc];
      *(uint4*)((unsigned short*)wqT + (size_t)(c0 + cc) * 512 + r0 + g * 8) = o.u;
    }
  }
}

// ---------------------------------------------------------------------------
// k3: 128x128 bf16 GEMM (W2 = M2 @ wqT^T). Rows >= msplit go to Calt.
// ---------------------------------------------------------------------------
template <typename TO>
__global__ __launch_bounds__(256, 4)
void gemm_bt(const bf16* __restrict__ A, int lda,
             const bf16* __restrict__ W, int mTiles,
             TO* __restrict__ C, int ldc, int K,
             TO* __restrict__ Calt, int msplit) {
  __shared__ __align__(16) bf16 As[128 * 64];
  __shared__ __align__(16) bf16 Bs[128 * 64];

  const int tid    = threadIdx.x;
  const int p      = blockIdx.x;
  const int m_tile = p % mTiles;
  const int n_tile = p / mTiles;
  const int m0     = m_tile * 128;
  const int n0     = n_tile * 128;

  const int wave = tid >> 6;
  const int lane = tid & 63;
  const int wr   = (wave >> 1) * 64;
  const int wc   = (wave & 1) * 64;
  const int quad = lane >> 4;
  const int r16  = lane & 15;
  const int rxor = r16 & 7;
  const int lrow = lane >> 3;
  const int lcol = lane & 7;
  const int gchunk = lcol ^ lrow;

  floatx4 acc[4][4];
#pragma unroll
  for (int i = 0; i < 4; ++i)
#pragma unroll
    for (int j = 0; j < 4; ++j) acc[i][j] = (floatx4)0.0f;

  const int ksteps = K >> 6;
  for (int kt = 0; kt < ksteps; ++kt) {
    const int k0 = kt << 6;
#pragma unroll
    for (int t = 0; t < 4; ++t) {
      const int s   = wave * 4 + t;
      const int row = s * 8 + lrow;
      gload_lds16(A + (size_t)(m0 + row) * lda + k0 + gchunk * 8, As + s * 512);
      gload_lds16(W + (size_t)(n0 + row) * K   + k0 + gchunk * 8, Bs + s * 512);
    }
    __syncthreads();
#pragma unroll
    for (int kk = 0; kk < 64; kk += 32) {
      const int cbase = kk >> 3;
      short8 af[4], bfg[4];
#pragma unroll
      for (int i = 0; i < 4; ++i)
        af[i] = *(const short8*)(As + (wr + i * 16 + r16) * 64 + (((quad + cbase) ^ rxor) << 3));
#pragma unroll
      for (int j = 0; j < 4; ++j)
        bfg[j] = *(const short8*)(Bs + (wc + j * 16 + r16) * 64 + (((quad + cbase) ^ rxor) << 3));
#pragma unroll
      for (int i = 0; i < 4; ++i)
#pragma unroll
        for (int j = 0; j < 4; ++j)
          acc[i][j] = __builtin_amdgcn_mfma_f32_16x16x32_bf16(af[i], bfg[j], acc[i][j], 0, 0, 0);
    }
    __syncthreads();
  }

  TO* Cb = C; int radj = 0;
  if (Calt && m0 >= msplit) { Cb = Calt; radj = msplit; }
#pragma unroll
  for (int j = 0; j < 4; ++j) {
    const int col = n0 + wc + j * 16 + r16;
#pragma unroll
    for (int i = 0; i < 4; ++i) {
      const int rowb = m0 + wr + i * 16 + quad * 4 - radj;
#pragma unroll
      for (int r = 0; r < 4; ++r)
        Cb[(size_t)(rowb + r) * ldc + col] = __float2bfloat16(acc[i][j][r]);
    }
  }
}

// ---------------------------------------------------------------------------
// k4: out = bf16(A_fp32) @ W2[batch]^T + bias. 128x128 tiles, grid 1024,
// XCD-swizzled; A fp32 reg-staged (single set, B async) — same pattern as k1.
// ---------------------------------------------------------------------------
__global__ __launch_bounds__(256, 4)
void gemm_f32a(const float* __restrict__ A,
               const bf16* __restrict__ W, size_t wbatch,
               const bf16* __restrict__ Walt,
               const float* __restrict__ bias,
               float* __restrict__ C, int ldc) {
  __shared__ __align__(16) bf16 As[128 * 64];
  __shared__ __align__(16) bf16 Bs[128 * 64];

  const int tid    = threadIdx.x;
  const int p      = blockIdx.x;
  const int n_tile = (p >> 3) & 7;
  const int m_tile = (p & 7) + (p >> 6) * 8;   // 0..127, XCD-contiguous
  const int m0 = m_tile * 128, n0 = n_tile * 128;
  const int batch = m_tile >> 5;
  const bf16* Wp = (batch == 3 && Walt) ? Walt : W + (size_t)batch * wbatch;

  const int wave = tid >> 6;
  const int lane = tid & 63;
  const int wr   = (wave >> 1) * 64;
  const int wc   = (wave & 1) * 64;
  const int quad = lane >> 4;
  const int r16  = lane & 15;
  const int rxor = r16 & 7;
  const int lrow = lane >> 3;
  const int lcol = lane & 7;
  const int gchunk = lcol ^ lrow;
  const int wb = wave * 8 + lrow;

  const float* Ax = A + (size_t)(m0 + wb) * 1024 + lcol * 8;

  floatx4 acc[4][4];
#pragma unroll
  for (int i = 0; i < 4; ++i)
#pragma unroll
    for (int j = 0; j < 4; ++j) acc[i][j] = (floatx4)0.0f;

  for (int kt = 0; kt < 16; ++kt) {
    const int k0 = kt << 6;
#pragma unroll
    for (int t = 0; t < 4; ++t) {
      const int s   = wave * 4 + t;
      const int row = s * 8 + lrow;
      gload_lds16(Wp + (size_t)(n0 + row) * 1024 + k0 + gchunk * 8, Bs + s * 512);
    }
    float4 rA[8];
#pragma unroll
    for (int l = 0; l < 4; ++l) {
      rA[2 * l]     = *(const float4*)(Ax + (size_t)l * 32768 + k0);
      rA[2 * l + 1] = *(const float4*)(Ax + (size_t)l * 32768 + k0 + 4);
    }
#pragma unroll
    for (int l = 0; l < 4; ++l) {
      const int row = l * 32 + wb;       // row&7 == lrow
      *(uint4*)(As + row * 64 + ((lcol ^ lrow) << 3)) = pack8(rA[2 * l], rA[2 * l + 1]);
    }
    __syncthreads();   // drains vm (Bs landed) + lgkm (As writes visible)
#pragma unroll
    for (int kk = 0; kk < 64; kk += 32) {
      const int cbase = kk >> 3;
      short8 af[4], bfg[4];
#pragma unroll
      for (int i = 0; i < 4; ++i)
        af[i] = *(const short8*)(As + (wr + i * 16 + r16) * 64 + (((quad + cbase) ^ rxor) << 3));
#pragma unroll
      for (int j = 0; j < 4; ++j)
        bfg[j] = *(const short8*)(Bs + (wc + j * 16 + r16) * 64 + (((quad + cbase) ^ rxor) << 3));
#pragma unroll
      for (int i = 0; i < 4; ++i)
#pragma unroll
        for (int j = 0; j < 4; ++j)
          acc[i][j] = __builtin_amdgcn_mfma_f32_16x16x32_bf16(af[i], bfg[j], acc[i][j], 0, 0, 0);
    }
    __syncthreads();
  }

  // D mapping (verified m89/m91): row = quad*4 + reg, col = lane&15
#pragma unroll
  for (int j = 0; j < 4; ++j) {
    const int col = n0 + wc + j * 16 + r16;
    const float bv = bias[col];
#pragma unroll
    for (int i = 0; i < 4; ++i) {
      const int rowb = m0 + wr + i * 16 + quad * 4;
#pragma unroll
      for (int r = 0; r < 4; ++r)
        C[(size_t)(rowb + r) * ldc + col] = acc[i][j][r] + bv;
    }
  }
}

// ---------------------------------------------------------------------------
extern "C" void kernel_launch(void* const* d_in, const int* in_sizes, int n_in,
                              void* d_out, int out_size, void* d_ws, size_t ws_size,
                              hipStream_t stream) {
  const float* x     = (const float*)d_in[0];
  const float* w_qkv = (const float*)d_in[1];
  const float* w_out = (const float*)d_in[2];
  const float* b_out = (const float*)d_in[3];
  float* out = (float*)d_out;

  char* wbuf = (char*)d_in[1];
  char* obuf = (char*)d_out;

  float* ctxp = (float*)obuf;                        // d_out[0,16)
  bf16*  M2   = (bf16*)(obuf + (size_t)16777216);    // d_out[16,20)
  bf16*  wqT  = (bf16*)(obuf + (size_t)20971520);    // d_out[20,20.5)
  bf16*  wkvb = (bf16*)(obuf + (size_t)23068672);    // d_out[22,24)
  bf16*  W2   = (bf16*)wbuf;                         // wbuf[0,6): batches 0-2
  bf16*  W2b3 = (bf16*)d_in[2];                      // w_out buf: batch 3

  // k0) wkvb = bf16(w_kv) — 2 MB convert
  conv_wkv<<<512, 256, 0, stream>>>(w_qkv, wkvb);

  // k1) fused kv-GEMM + softmax + ctx partials (A fp32 reg, B bf16 async)
  kv_softmax_ctx<<<1024, 256, 0, stream>>>(x, wkvb, ctxp);

  // k2) merged: M2 = w_out folded through summed ctx; wqT = wq^T
  build_m2_wqt<<<384, 256, 0, stream>>>(w_out, ctxp, w_qkv, M2, wqT);

  // k3) W2 = M2 @ wqT^T; rows<3072 -> wbuf[0,6), rows>=3072 -> w_out buf.
  gemm_bt<bf16><<<256, 256, 0, stream>>>(
      M2, 512, wqT, 32, W2, 1024, 512, W2b3, 3072);

  // k4) out = bf16(x) @ W2[b]^T + b_out -> d_out (reads nothing in d_out).
  gemm_f32a<<<1024, 256, 0, stream>>>(
      x, W2, (size_t)1048576, W2b3, b_out, out, DIM);
}